// Round 5
// baseline (203.194 us; speedup 1.0000x reference)
//
#include <hip/hip_runtime.h>
#include <hip/hip_bf16.h>
#include <cmath>

#define NTOK 1728
#define DIMC 128
#define NHEAD 8
#define NB 4
#define TABN 12167
#define TSTRIDE 12168
#define NBLK 216
#define SLDSN 6656   // max idx window = 517 + 6084 = 6601, padded

typedef __attribute__((ext_vector_type(8))) short bf16x8;
typedef __attribute__((ext_vector_type(4))) float f32x4;

static __device__ __forceinline__ unsigned short f2bf(float f) {
    union { float f; unsigned u; } v; v.f = f;
    unsigned r = v.u + 0x7fff + ((v.u >> 16) & 1);   // RNE
    return (unsigned short)(r >> 16);
}
static __device__ __forceinline__ int Pdec(int t) {
    return (t / 144) * 529 + ((t / 12) % 12) * 23 + (t % 12);
}

// device-scope grid barrier: co-residency guaranteed (216 blocks, 1/CU)
static __device__ __forceinline__ void gridbar(unsigned* C, int id) {
    __syncthreads();
    if (threadIdx.x == 0) {
        __threadfence();                       // release (L2 wb for cross-XCD)
        atomicAdd(&C[id], 1u);
        while (__hip_atomic_load(&C[id], __ATOMIC_RELAXED,
                                 __HIP_MEMORY_SCOPE_AGENT) < (unsigned)NBLK)
            __builtin_amdgcn_s_sleep(8);
        __threadfence();                       // acquire (L1/L2 inv)
    }
    __syncthreads();
}

__global__ __launch_bounds__(512, 2) void k_mega(
    const float* __restrict__ x, const float* __restrict__ Wq,
    const float* __restrict__ Wk, const float* __restrict__ Wv,
    const float* __restrict__ Wp, const float* __restrict__ bp,
    const float* __restrict__ tbl,
    unsigned* C, float* n1, unsigned short* tblT,
    float* QS, float* Ko, float* Vo, unsigned short* EKVt,
    float* Yb, float* out)
{
    __shared__ __align__(16) unsigned char LDSU[98304];   // 96 KB
    const int t = threadIdx.x;
    const int sub = t >> 8, ts = t & 255;
    const int slot = (int)blockIdx.x * 2 + sub;           // 0..431

    // ================= P1: q/k/v projections =================
    // slot = (row-tile 0..107, cg 0..3); loop m = 0..2 reusing staged x tile
    {
        float* S  = (float*)(LDSU + sub * 49152);
        float* xs = S;               // 64x128 swizzled
        float* Ws = S + 64 * 128;    // 32x128
        const int rt = slot >> 2, cg = slot & 3;
        const int row0 = rt * 64;
        {
            const int cc = ts & 31;
            #pragma unroll
            for (int p = 0; p < 8; ++p) {
                const int r = (ts >> 5) + p * 8;
                float4 v = *(const float4*)&x[(size_t)(row0 + r) * DIMC + cc * 4];
                *(float4*)&xs[r * 128 + ((cc * 4) ^ ((r & 7) << 2))] = v;
            }
        }
        #pragma unroll 1
        for (int m = 0; m < 3; ++m) {
            const float* __restrict__ W = (m == 0) ? Wq : (m == 1) ? Wk : Wv;
            __syncthreads();                    // prev res-reads / xs stage done
            {
                const int cc = ts & 31;
                #pragma unroll
                for (int p = 0; p < 4; ++p) {
                    const int c = (ts >> 5) + p * 8;
                    float4 v = *(const float4*)&W[(size_t)(cg * 32 + c) * DIMC + cc * 4];
                    *(float4*)&Ws[c * 128 + cc * 4] = v;
                }
            }
            __syncthreads();
            const int nl = ts & 63, wx = ts >> 6;
            float acc[8];
            #pragma unroll
            for (int c = 0; c < 8; ++c) acc[c] = 0.f;
            for (int k4 = 0; k4 < 32; ++k4) {
                const float4 xv = *(const float4*)&xs[nl * 128 + ((k4 * 4) ^ ((nl & 7) << 2))];
                #pragma unroll
                for (int c = 0; c < 8; ++c) {
                    const float4 wv = *(const float4*)&Ws[(wx * 8 + c) * 128 + k4 * 4];
                    acc[c] = fmaf(xv.x, wv.x, fmaf(xv.y, wv.y,
                             fmaf(xv.z, wv.z, fmaf(xv.w, wv.w, acc[c]))));
                }
            }
            if (m == 0) {
                #pragma unroll
                for (int c = 0; c < 8; ++c) acc[c] = 1.f / (1.f + expf(-acc[c]));
            }
            __syncthreads();                    // Ws reads done before bounce
            #pragma unroll
            for (int c = 0; c < 8; ++c) Ws[nl * 33 + wx * 8 + c] = acc[c];
            __syncthreads();
            float* __restrict__ Out = (m == 0) ? QS : (m == 1) ? Ko : Vo;
            const int r = ts >> 2, q = ts & 3;
            float4 v0, v1;
            v0.x = Ws[r*33 + q*8 + 0]; v0.y = Ws[r*33 + q*8 + 1];
            v0.z = Ws[r*33 + q*8 + 2]; v0.w = Ws[r*33 + q*8 + 3];
            v1.x = Ws[r*33 + q*8 + 4]; v1.y = Ws[r*33 + q*8 + 5];
            v1.z = Ws[r*33 + q*8 + 6]; v1.w = Ws[r*33 + q*8 + 7];
            *(float4*)&Out[(size_t)(row0 + r) * DIMC + cg * 32 + q * 8] = v0;
            *(float4*)&Out[(size_t)(row0 + r) * DIMC + cg * 32 + q * 8 + 4] = v1;
        }
    }
    gridbar(C, 0);

    // ================= P2: EKVt + n1 colsums | table prep =================
    if (slot < 216) {       // block-uniform (216 even)
        float (*red)[33] = (float (*)[33])(LDSU + sub * 49152);
        const int jx = slot % 27, h = slot / 27;
        const int b = ts >> 6, jj = ts & 63;
        const int j = jx * 64 + jj;
        const float* kp = &Ko[((size_t)b * NTOK + j) * DIMC + h * 16];
        const float* vp = &Vo[((size_t)b * NTOK + j) * DIMC + h * 16];
        float kv[16], vv[16], ob[32];
        #pragma unroll
        for (int d4 = 0; d4 < 4; ++d4) {
            *(float4*)&kv[d4 * 4] = *(const float4*)&kp[d4 * 4];
            *(float4*)&vv[d4 * 4] = *(const float4*)&vp[d4 * 4];
        }
        #pragma unroll
        for (int d = 0; d < 16; ++d) {
            float e = expf(kv[d]);              // kmax/bmax cancel in num/den
            ob[d] = e * vv[d];
            ob[16 + d] = e;
        }
        #pragma unroll
        for (int c = 0; c < 32; ++c)
            EKVt[((size_t)h * DIMC + b * 32 + c) * NTOK + j] = f2bf(ob[c]);
        #pragma unroll
        for (int c = 0; c < 32; ++c) red[ts][c] = ob[c];
        __syncthreads();
        if (ts < 128) {
            const int b2 = ts >> 5, c = ts & 31;
            float s = 0.f;
            for (int r = 0; r < 64; ++r) s += red[b2 * 64 + r][c];
            atomicAdd(&n1[(h * NB + b2) * 32 + c], s);
        }
    } else {                // table prep: tblT[h][idx] = bf16(expm1(tbl))
        const int base = (slot - 216) * 57;
        for (int v2 = ts; v2 < 456; v2 += 256) {
            const int ii = v2 >> 3, hh = v2 & 7;
            const int idx = base + ii;
            if (ii < 57 && idx < TABN)
                tblT[hh * TSTRIDE + idx] = f2bf(expm1f(tbl[idx * 8 + hh]));
        }
        __syncthreads();
    }
    gridbar(C, 1);

    // ================= P3: MFMA einsum + finalize Y (no part buffer) ========
    // block = (i-tile, h); 2 parity groups of 4 waves split j-tiles in-block
    {
        const int ti = (int)blockIdx.x % 27, h = (int)blockIdx.x / 27;
        const int i0 = ti * 64;
        unsigned short* slds = (unsigned short*)LDSU;                    // 13312 B
        unsigned short* alds = (unsigned short*)(LDSU + 13312 + sub * 24576);
        unsigned short* blds = alds + 64 * 64;
        float* rbuf = (float*)(LDSU + 13312 + 24576);   // reuse parity-1 region

        const int idx_lo = Pdec(i0);     // = P(i0)+6083-P(1727)
        {
            const unsigned short* src = &tblT[(size_t)h * TSTRIDE];
            for (int s = t; s < SLDSN; s += 512) {
                const int g = idx_lo + s;
                slds[s] = (g < TSTRIDE) ? src[g] : (unsigned short)0;
            }
        }
        const int w = ts >> 6, l = ts & 63;
        const int il = l & 15, kg = l >> 4;
        const int gi0 = w * 16;
        int qb[16];
        #pragma unroll
        for (int r = 0; r < 16; ++r) qb[r] = Pdec(i0 + gi0 + r) + 6083 - idx_lo;
        const int bc = ts >> 3, bj8 = (ts & 7) * 8;

        f32x4 acc[8];
        #pragma unroll
        for (int cf = 0; cf < 8; ++cf) acc[cf] = (f32x4){0.f, 0.f, 0.f, 0.f};

        #pragma unroll 1
        for (int jt = 0; jt < 14; ++jt) {
            const int j0 = (2 * jt + sub) * 64;   // parity-interleaved j-tiles
            const bool act = (j0 < NTOK);
            __syncthreads();
            if (act) {
                #pragma unroll
                for (int pp = 0; pp < 4; ++pp) {
                    const int c = bc + pp * 32;
                    bf16x8 v = *(const bf16x8*)&EKVt[((size_t)h * DIMC + c) * NTOK + j0 + bj8];
                    *(bf16x8*)&blds[c * 64 + (bj8 ^ ((c & 7) << 3))] = v;
                }
                const int pj = Pdec(j0 + l);
                #pragma unroll
                for (int r = 0; r < 16; ++r)
                    alds[(gi0 + r) * 64 + (l ^ ((r & 7) << 3))] = slds[qb[r] - pj];
            }
            __syncthreads();
            if (act) {
                #pragma unroll
                for (int kk = 0; kk < 2; ++kk) {
                    const int ia = w * 16 + il;
                    const int ka = kk * 32 + kg * 8;
                    bf16x8 af = *(const bf16x8*)&alds[ia * 64 + (ka ^ ((ia & 7) << 3))];
                    #pragma unroll
                    for (int cf = 0; cf < 8; ++cf) {
                        const int cb = cf * 16 + il;
                        bf16x8 bfv = *(const bf16x8*)&blds[cb * 64 + (ka ^ ((cb & 7) << 3))];
                        acc[cf] = __builtin_amdgcn_mfma_f32_16x16x32_bf16(af, bfv, acc[cf], 0, 0, 0);
                    }
                }
            }
        }
        __syncthreads();
        if (sub == 1) {     // parity-1 exports partial sums
            #pragma unroll
            for (int cf = 0; cf < 8; ++cf)
                *(f32x4*)&rbuf[ts * 36 + cf * 4] = acc[cf];
        }
        __syncthreads();
        if (sub == 0) {     // parity-0 reduces + finalizes y = sig(q)*num/den
            #pragma unroll
            for (int cf = 0; cf < 8; ++cf) {
                f32x4 o = *(const f32x4*)&rbuf[ts * 36 + cf * 4];
                acc[cf][0] += o[0]; acc[cf][1] += o[1];
                acc[cf][2] += o[2]; acc[cf][3] += o[3];
            }
            #pragma unroll
            for (int e = 0; e < 4; ++e) {       // e = batch b (c = e*32 + cc)
                const float nn0 = n1[(h * NB + e) * 32 + il];
                const float dd0 = n1[(h * NB + e) * 32 + 16 + il];
                #pragma unroll
                for (int r = 0; r < 4; ++r) {
                    const int i = i0 + w * 16 + kg * 4 + r;
                    const size_t off = ((size_t)e * NTOK + i) * DIMC + h * 16 + il;
                    const float nn = nn0 + acc[2 * e][r];
                    const float dd = dd0 + acc[2 * e + 1][r];
                    Yb[off] = QS[off] * nn / dd;
                }
            }
        }
    }
    gridbar(C, 2);

    // ================= P4: out = Y @ Wp^T + bp =================
    {
        float* S  = (float*)(LDSU + sub * 49152);
        float* xs = S;
        float* Ws = S + 64 * 128;
        const int rt = slot >> 2, cg = slot & 3;
        const int row0 = rt * 64;
        {
            const int cc = ts & 31;
            #pragma unroll
            for (int p = 0; p < 8; ++p) {
                const int r = (ts >> 5) + p * 8;
                float4 v = *(const float4*)&Yb[(size_t)(row0 + r) * DIMC + cc * 4];
                *(float4*)&xs[r * 128 + ((cc * 4) ^ ((r & 7) << 2))] = v;
            }
        }
        {
            const int cc = ts & 31;
            #pragma unroll
            for (int p = 0; p < 4; ++p) {
                const int c = (ts >> 5) + p * 8;
                float4 v = *(const float4*)&Wp[(size_t)(cg * 32 + c) * DIMC + cc * 4];
                *(float4*)&Ws[c * 128 + cc * 4] = v;
            }
        }
        __syncthreads();
        const int nl = ts & 63, wx = ts >> 6;
        float acc[8];
        #pragma unroll
        for (int c = 0; c < 8; ++c) acc[c] = 0.f;
        for (int k4 = 0; k4 < 32; ++k4) {
            const float4 xv = *(const float4*)&xs[nl * 128 + ((k4 * 4) ^ ((nl & 7) << 2))];
            #pragma unroll
            for (int c = 0; c < 8; ++c) {
                const float4 wv = *(const float4*)&Ws[(wx * 8 + c) * 128 + k4 * 4];
                acc[c] = fmaf(xv.x, wv.x, fmaf(xv.y, wv.y,
                         fmaf(xv.z, wv.z, fmaf(xv.w, wv.w, acc[c]))));
            }
        }
        #pragma unroll
        for (int c = 0; c < 8; ++c) acc[c] += bp[cg * 32 + wx * 8 + c];
        __syncthreads();
        #pragma unroll
        for (int c = 0; c < 8; ++c) Ws[nl * 33 + wx * 8 + c] = acc[c];
        __syncthreads();
        const int r = ts >> 2, q = ts & 3;
        float4 v0, v1;
        v0.x = Ws[r*33 + q*8 + 0]; v0.y = Ws[r*33 + q*8 + 1];
        v0.z = Ws[r*33 + q*8 + 2]; v0.w = Ws[r*33 + q*8 + 3];
        v1.x = Ws[r*33 + q*8 + 4]; v1.y = Ws[r*33 + q*8 + 5];
        v1.z = Ws[r*33 + q*8 + 6]; v1.w = Ws[r*33 + q*8 + 7];
        *(float4*)&out[(size_t)(row0 + r) * DIMC + cg * 32 + q * 8] = v0;
        *(float4*)&out[(size_t)(row0 + r) * DIMC + cg * 32 + q * 8 + 4] = v1;
    }
}

extern "C" void kernel_launch(void* const* d_in, const int* in_sizes, int n_in,
                              void* d_out, int out_size, void* d_ws, size_t ws_size,
                              hipStream_t stream) {
    const float* x    = (const float*)d_in[0];
    const float* Wq   = (const float*)d_in[1];
    const float* Wk   = (const float*)d_in[2];
    const float* Wv   = (const float*)d_in[3];
    const float* Wp   = (const float*)d_in[4];
    const float* bp   = (const float*)d_in[5];
    const float* tbl  = (const float*)d_in[6];

    float* ws = (float*)d_ws;
    unsigned* C = (unsigned*)ws;                        // 16 u32 barrier counters
    float* n1 = ws + 16;                                // 1024 f32
    unsigned short* tblT = (unsigned short*)(ws + 16 + 1024);   // 97344 u16
    float* QS = ws + 16 + 1024 + 48672;
    float* Ko = QS + 884736;
    float* Vo = Ko + 884736;
    unsigned short* EKVt = (unsigned short*)(Vo + 884736);      // 1769472 u16
    float* Yb = Vo + 884736 + 884736;

    hipMemsetAsync(ws, 0, (16 + 1024) * sizeof(float), stream);  // counters + n1
    k_mega<<<dim3(NBLK), 512, 0, stream>>>(x, Wq, Wk, Wv, Wp, bp, tbl,
                                           C, n1, tblT, QS, Ko, Vo, EKVt, Yb,
                                           (float*)d_out);
}